// Round 6
// baseline (287.682 us; speedup 1.0000x reference)
//
#include <hip/hip_runtime.h>

typedef short bf16x8 __attribute__((ext_vector_type(8)));
typedef float f32x4 __attribute__((ext_vector_type(4)));
typedef unsigned short u16x8 __attribute__((ext_vector_type(8)));

static __device__ __forceinline__ unsigned short f2bf(float f) {
  unsigned int x = __builtin_bit_cast(unsigned int, f);
  x += 0x7FFFu + ((x >> 16) & 1u);   // RNE
  return (unsigned short)(x >> 16);
}
// pack two floats' bf16 (round-half-up) into one u32 (lo=a, hi=b)
static __device__ __forceinline__ unsigned int pk2bf(float a, float b) {
  unsigned int ia = __builtin_bit_cast(unsigned int, a) + 0x8000u;
  unsigned int ib = __builtin_bit_cast(unsigned int, b) + 0x8000u;
  return __builtin_amdgcn_perm(ib, ia, 0x07060302u);
}
static __device__ __forceinline__ uint4 pk8bf(float4 a, float4 b) {
  uint4 r;
  r.x = pk2bf(a.x, a.y); r.y = pk2bf(a.z, a.w);
  r.z = pk2bf(b.x, b.y); r.w = pk2bf(b.z, b.w);
  return r;
}
// async 16B global -> LDS (per-wave: lane i writes ldsbase+i*16; pass per-lane ptr computed consistently)
static __device__ __forceinline__ void gl2lds16(const unsigned short* g, unsigned short* l) {
  __builtin_amdgcn_global_load_lds(
      (const __attribute__((address_space(1))) unsigned int*)g,
      (__attribute__((address_space(3))) unsigned int*)l, 16, 0, 0);
}

// ------- 4x W [512k][512n] f32 -> WT [4][512n][512k] bf16 (z selects matrix) -------
__global__ __launch_bounds__(256) void wtrans4(const float* __restrict__ Wq, const float* __restrict__ Wk,
                                               const float* __restrict__ Wv, const float* __restrict__ Wo,
                                               unsigned short* __restrict__ WT) {
  __shared__ __align__(16) float T[64 * 68];
  const int z = blockIdx.z;
  const float* W = (z == 0) ? Wq : (z == 1) ? Wk : (z == 2) ? Wv : Wo;
  unsigned short* out = WT + (size_t)z * 512 * 512;
  const int k0 = blockIdx.x * 64, n0 = blockIdx.y * 64;
  const int tid = threadIdx.x;
#pragma unroll
  for (int i = 0; i < 4; ++i) {
    int chunk = i * 256 + tid;
    int row = chunk >> 4, fc = chunk & 15;
    *(float4*)(T + row * 68 + fc * 4) =
        *(const float4*)(W + (size_t)(k0 + row) * 512 + n0 + fc * 4);
  }
  __syncthreads();
#pragma unroll
  for (int i = 0; i < 2; ++i) {
    int chunk = i * 256 + tid;
    int nr = chunk >> 3, kc = chunk & 7;
    u16x8 v;
#pragma unroll
    for (int j = 0; j < 8; ++j) v[j] = f2bf(T[(kc * 8 + j) * 68 + nr]);
    *(u16x8*)(out + (size_t)(n0 + nr) * 512 + k0 + kc * 8) = v;
  }
}

// ---- fused cvt+QKV GEMM: C[8192][1536]. A = fp32 q/k/v (converted in staging).
// 128x128 tile, BK=32, 4x4 acc/wave. grid (12 by-major, 64 bm). ----
__global__ __launch_bounds__(256) void gemm_qkv(const float* __restrict__ Aq, const float* __restrict__ Ak,
                                                const float* __restrict__ Av,
                                                const unsigned short* __restrict__ Bt,
                                                unsigned short* __restrict__ C, float qscale) {
  __shared__ __align__(16) unsigned short Abuf[2][128 * 32];
  __shared__ __align__(16) unsigned short Bbuf[2][128 * 32];
  const int by = blockIdx.x;
  const float* A = (by < 4) ? Aq : (by < 8) ? Ak : Av;
  const float scale = (by < 4) ? qscale : 1.0f;
  const int tid = threadIdx.x;
  const int wid = tid >> 6, lane = tid & 63, quad = lane >> 4, li = lane & 15;
  const int bm = blockIdx.y * 128, bn = by * 128;
  const int wm = (wid & 1) * 64, wn = (wid >> 1) * 64;
  // B staging (async): 512 chunks, 2/thread
  const unsigned short* gb[2]; int obx[2];
#pragma unroll
  for (int i = 0; i < 2; ++i) {
    int lam = i * 256 + tid;
    int r = lam >> 2, cc = (lam & 3) ^ (r & 3);
    gb[i] = Bt + (size_t)(bn + r) * 512 + cc * 8;
    obx[i] = lam * 8;
  }
  // A staging (fp32->bf16 via VGPR): 512 chunks, 2/thread
  int ar[2], ac[2], ao[2];
#pragma unroll
  for (int i = 0; i < 2; ++i) {
    int c = i * 256 + tid;
    ar[i] = c >> 2;
    ac[i] = ((c & 3) ^ (ar[i] & 3)) * 8;
    ao[i] = c * 8;
  }
  float4 av0[2], av1[2];
  // prologue: stage step 0
#pragma unroll
  for (int i = 0; i < 2; ++i) {
    const float* ap = A + (size_t)(bm + ar[i]) * 512 + ac[i];
    av0[i] = *(const float4*)ap;
    av1[i] = *(const float4*)(ap + 4);
  }
#pragma unroll
  for (int i = 0; i < 2; ++i) *(uint4*)(&Abuf[0][ao[i]]) = pk8bf(av0[i], av1[i]);
#pragma unroll
  for (int i = 0; i < 2; ++i) { gl2lds16(gb[i], &Bbuf[0][obx[i]]); gb[i] += 32; }

  f32x4 acc[4][4] = {};
  const int sw = li & 3;
  for (int s = 0; s < 16; ++s) {
    __syncthreads();
    const bool pf = (s + 1 < 16);
    const int p = (s + 1) & 1;
    if (pf) {
#pragma unroll
      for (int i = 0; i < 2; ++i) { gl2lds16(gb[i], &Bbuf[p][obx[i]]); gb[i] += 32; }
#pragma unroll
      for (int i = 0; i < 2; ++i) {
        const float* ap = A + (size_t)(bm + ar[i]) * 512 + (s + 1) * 32 + ac[i];
        av0[i] = *(const float4*)ap;
        av1[i] = *(const float4*)(ap + 4);
      }
    }
    const unsigned short* As = &Abuf[s & 1][0];
    const unsigned short* Bs = &Bbuf[s & 1][0];
    bf16x8 af[4], bfr[4];
#pragma unroll
    for (int t = 0; t < 4; ++t) {
      af[t]  = *(const bf16x8*)(As + (wm + t * 16 + li) * 32 + ((quad ^ sw) * 8));
      bfr[t] = *(const bf16x8*)(Bs + (wn + t * 16 + li) * 32 + ((quad ^ sw) * 8));
    }
#pragma unroll
    for (int mt = 0; mt < 4; ++mt)
#pragma unroll
      for (int nt = 0; nt < 4; ++nt)
        acc[mt][nt] = __builtin_amdgcn_mfma_f32_16x16x32_bf16(af[mt], bfr[nt], acc[mt][nt], 0, 0, 0);
    if (pf) {
#pragma unroll
      for (int i = 0; i < 2; ++i) *(uint4*)(&Abuf[p][ao[i]]) = pk8bf(av0[i], av1[i]);
    }
  }
#pragma unroll
  for (int mt = 0; mt < 4; ++mt)
#pragma unroll
    for (int nt = 0; nt < 4; ++nt) {
      int r0 = bm + wm + mt * 16 + quad * 4;
      int c  = bn + wn + nt * 16 + li;
#pragma unroll
      for (int r = 0; r < 4; ++r)
        C[(size_t)(r0 + r) * 1536 + c] = f2bf(acc[mt][nt][r] * scale);
    }
}

// ---- qkvh V-section -> vt [(b*8+h)*64+d][4096] (per-head V^T) ----
__global__ __launch_bounds__(256) void vtrans(const unsigned short* __restrict__ qkv,
                                              unsigned short* __restrict__ vt) {
  __shared__ __align__(16) unsigned short T[64 * 72];
  const int kt = blockIdx.x;
  const int bh = blockIdx.y;
  const int b = bh >> 3, h = bh & 7;
  const int tid = threadIdx.x;
#pragma unroll
  for (int i = 0; i < 2; ++i) {
    int chunk = i * 256 + tid;
    int row = chunk >> 3, c8 = chunk & 7;
    *(uint4*)(T + row * 72 + c8 * 8) =
        *(const uint4*)(qkv + (size_t)(b * 4096 + kt * 64 + row) * 1536 + 1024 + h * 64 + c8 * 8);
  }
  __syncthreads();
#pragma unroll
  for (int i = 0; i < 2; ++i) {
    int chunk = i * 256 + tid;
    int dr = chunk >> 3, c8 = chunk & 7;
    u16x8 v;
#pragma unroll
    for (int j = 0; j < 8; ++j) v[j] = T[(c8 * 8 + j) * 72 + dr];
    *(u16x8*)(vt + (size_t)(bh * 64 + dr) * 4096 + kt * 64 + c8 * 8) = v;
  }
}

// ---- split-K flash attention: 4 waves x 32 queries (2 q-sets/wave), S^T form,
// no-max softmax, l-via-ones-MFMA. block = (qt:128q, h, b*2+half); 256 threads.
// K/V frag reads serve BOTH q-sets -> ~1.6x less LDS traffic (LDS-BW-bound). ----
__global__ __launch_bounds__(256) void attn(const unsigned short* __restrict__ qkv,
                                            const unsigned short* __restrict__ vt,
                                            const int* __restrict__ mask,
                                            float* __restrict__ O0, float* __restrict__ O1,
                                            float* __restrict__ Lb) {
  __shared__ __align__(16) unsigned short Kbuf[2][64 * 64];
  __shared__ __align__(16) unsigned short Vbuf[2][64 * 64];
  __shared__ __align__(16) unsigned short Psh[4][32 * 72];
  __shared__ __align__(16) unsigned short MskBits[256];
  const int qt = blockIdx.x, h = blockIdx.y, z = blockIdx.z;
  const int b = z >> 1, half = z & 1;
  const int t0 = half * 32;
  const int tid = threadIdx.x;
  const int wid = tid >> 6, lane = tid & 63, quad = lane >> 4, li = lane & 15;
  const size_t tok0 = (size_t)b * 4096;

  {
    const int4* mp = (const int4*)(mask + b * 4096 + tid * 16);
    unsigned int bits = 0;
#pragma unroll
    for (int j = 0; j < 4; ++j) {
      int4 m4 = mp[j];
      bits |= (m4.x ? 1u : 0u) << (j * 4 + 0);
      bits |= (m4.y ? 1u : 0u) << (j * 4 + 1);
      bits |= (m4.z ? 1u : 0u) << (j * 4 + 2);
      bits |= (m4.w ? 1u : 0u) << (j * 4 + 3);
    }
    MskBits[tid] = (unsigned short)bits;
  }

  // two Q B-operand sets per wave: rows wid*32+li and wid*32+16+li
  const unsigned short* qpa = qkv + (tok0 + qt * 128 + wid * 32 + li) * 1536 + h * 64;
  const unsigned short* qpb = qpa + 16 * 1536;
  bf16x8 bq0a = *(const bf16x8*)(qpa + quad * 8);
  bf16x8 bq1a = *(const bf16x8*)(qpa + 32 + quad * 8);
  bf16x8 bq0b = *(const bf16x8*)(qpb + quad * 8);
  bf16x8 bq1b = *(const bf16x8*)(qpb + 32 + quad * 8);

  // staging: 4 chunks/thread (2 K + 2 V); per-wave-contiguous chunk ids
  const unsigned short* kbase = qkv + tok0 * 1536 + 512 + h * 64;
  const unsigned short* vbase = vt + (size_t)(b * 8 + h) * 64 * 4096;
  const unsigned short *gk[2], *gv[2];
  int okc[2], ovc[2];
#pragma unroll
  for (int i = 0; i < 2; ++i) {
    int c = i * 256 + tid;
    int r = c >> 3, cc = (c & 7) ^ (r & 7);
    gk[i] = kbase + (size_t)(t0 * 64 + r) * 1536 + cc * 8;
    gv[i] = vbase + (size_t)r * 4096 + t0 * 64 + cc * 8;
    okc[i] = c * 8;
    ovc[i] = c * 8;
  }
  // prologue: tile 0 into buf 0
#pragma unroll
  for (int i = 0; i < 2; ++i) {
    gl2lds16(gk[i], &Kbuf[0][okc[i]]); gk[i] += (size_t)64 * 1536;
    gl2lds16(gv[i], &Vbuf[0][ovc[i]]); gv[i] += 64;
  }

  f32x4 accOa[4] = {}, accOb[4] = {};
  f32x4 accLa = {}, accLb = {};
  bf16x8 bones;
#pragma unroll
  for (int j = 0; j < 8; ++j) bones[j] = (short)0x3F80;  // bf16 1.0
  unsigned short* Pw = &Psh[wid][0];
  const int sw = li & 7;

  for (int tt = 0; tt < 32; ++tt) {
    const int t = t0 + tt;
    __syncthreads();
    if (tt < 31) {
      const int p = (tt + 1) & 1;
#pragma unroll
      for (int i = 0; i < 2; ++i) {
        gl2lds16(gk[i], &Kbuf[p][okc[i]]); gk[i] += (size_t)64 * 1536;
        gl2lds16(gv[i], &Vbuf[p][ovc[i]]); gv[i] += 64;
      }
    }
    const unsigned short* Ks = &Kbuf[tt & 1][0];
    const unsigned short* Vs = &Vbuf[tt & 1][0];

    // S^T = K Q^T for both q-sets; K frags shared
    f32x4 sa[4], sb[4];
#pragma unroll
    for (int kb = 0; kb < 4; ++kb) {
      const unsigned short* kr = Ks + (kb * 16 + li) * 64;
      bf16x8 ak0 = *(const bf16x8*)(kr + ((quad ^ sw) * 8));
      bf16x8 ak1 = *(const bf16x8*)(kr + (((4 + quad) ^ sw) * 8));
      f32x4 za = {}, zb = {};
      za = __builtin_amdgcn_mfma_f32_16x16x32_bf16(ak0, bq0a, za, 0, 0, 0);
      za = __builtin_amdgcn_mfma_f32_16x16x32_bf16(ak1, bq1a, za, 0, 0, 0);
      zb = __builtin_amdgcn_mfma_f32_16x16x32_bf16(ak0, bq0b, zb, 0, 0, 0);
      zb = __builtin_amdgcn_mfma_f32_16x16x32_bf16(ak1, bq1b, zb, 0, 0, 0);
      sa[kb] = za; sb[kb] = zb;
    }
    unsigned long long mbits = *(const unsigned long long*)(MskBits + t * 4);
    if (mbits != ~0ull) {
#pragma unroll
      for (int kb = 0; kb < 4; ++kb)
#pragma unroll
        for (int r = 0; r < 4; ++r) {
          int key = kb * 16 + quad * 4 + r;
          if (!((mbits >> key) & 1ull)) { sa[kb][r] = -1e30f; sb[kb][r] = -1e30f; }
        }
    }
    // p = exp2(s); pack bf16 into per-wave P (set a rows li, set b rows li+16)
#pragma unroll
    for (int kb = 0; kb < 4; ++kb) {
#pragma unroll
      for (int r = 0; r < 4; ++r) {
        sa[kb][r] = __builtin_amdgcn_exp2f(sa[kb][r]);
        sb[kb][r] = __builtin_amdgcn_exp2f(sb[kb][r]);
      }
      uint2 pka, pkb;
      pka.x = pk2bf(sa[kb][0], sa[kb][1]); pka.y = pk2bf(sa[kb][2], sa[kb][3]);
      pkb.x = pk2bf(sb[kb][0], sb[kb][1]); pkb.y = pk2bf(sb[kb][2], sb[kb][3]);
      *(uint2*)(Pw + li * 72 + kb * 16 + quad * 4) = pka;
      *(uint2*)(Pw + (li + 16) * 72 + kb * 16 + quad * 4) = pkb;
    }
    // O += P V ; l += P * ones   (V frags shared between q-sets)
    bf16x8 p0a = *(const bf16x8*)(Pw + li * 72 + quad * 8);
    bf16x8 p1a = *(const bf16x8*)(Pw + li * 72 + 32 + quad * 8);
    bf16x8 p0b = *(const bf16x8*)(Pw + (li + 16) * 72 + quad * 8);
    bf16x8 p1b = *(const bf16x8*)(Pw + (li + 16) * 72 + 32 + quad * 8);
#pragma unroll
    for (int dc = 0; dc < 4; ++dc) {
      const unsigned short* vr = Vs + (dc * 16 + li) * 64;
      bf16x8 bv0 = *(const bf16x8*)(vr + ((quad ^ sw) * 8));
      bf16x8 bv1 = *(const bf16x8*)(vr + (((4 + quad) ^ sw) * 8));
      accOa[dc] = __builtin_amdgcn_mfma_f32_16x16x32_bf16(p0a, bv0, accOa[dc], 0, 0, 0);
      accOa[dc] = __builtin_amdgcn_mfma_f32_16x16x32_bf16(p1a, bv1, accOa[dc], 0, 0, 0);
      accOb[dc] = __builtin_amdgcn_mfma_f32_16x16x32_bf16(p0b, bv0, accOb[dc], 0, 0, 0);
      accOb[dc] = __builtin_amdgcn_mfma_f32_16x16x32_bf16(p1b, bv1, accOb[dc], 0, 0, 0);
    }
    accLa = __builtin_amdgcn_mfma_f32_16x16x32_bf16(p0a, bones, accLa, 0, 0, 0);
    accLa = __builtin_amdgcn_mfma_f32_16x16x32_bf16(p1a, bones, accLa, 0, 0, 0);
    accLb = __builtin_amdgcn_mfma_f32_16x16x32_bf16(p0b, bones, accLb, 0, 0, 0);
    accLb = __builtin_amdgcn_mfma_f32_16x16x32_bf16(p1b, bones, accLb, 0, 0, 0);
  }
  // epilogue: unnormalized fp32 partials + l
  float* Oh = half ? O1 : O0;
  const size_t rqa = tok0 + qt * 128 + wid * 32 + quad * 4;
  const size_t rqb = rqa + 16;
#pragma unroll
  for (int dc = 0; dc < 4; ++dc) {
    size_t col = h * 64 + dc * 16 + li;
#pragma unroll
    for (int r = 0; r < 4; ++r) {
      Oh[(rqa + r) * 512 + col] = accOa[dc][r];
      Oh[(rqb + r) * 512 + col] = accOb[dc][r];
    }
  }
  if (li == 0) {
#pragma unroll
    for (int r = 0; r < 4; ++r) {
      Lb[((size_t)half * 8192 + rqa + r) * 8 + h] = accLa[r];
      Lb[((size_t)half * 8192 + rqb + r) * 8 + h] = accLb[r];
    }
  }
}

// ---- O-proj GEMM with fused combine: out[8192][512] f32 = ((O0+O1)/l) * woT^T.
// A staged fp32->bf16 with per-(token,head) 1/(l0+l1) (h == step since BK=64).
// grid (8 bn-major, 64 bm). ----
__global__ __launch_bounds__(256) void gemm_o(const float* __restrict__ O0, const float* __restrict__ O1,
                                              const float* __restrict__ Lb,
                                              const unsigned short* __restrict__ Bt,
                                              float* __restrict__ Cf) {
  __shared__ __align__(16) unsigned short Abuf[2][128 * 64];
  __shared__ __align__(16) unsigned short Bbuf[2][64 * 64];
  const int tid = threadIdx.x;
  const int wid = tid >> 6, lane = tid & 63, quad = lane >> 4, li = lane & 15;
  const int bm = blockIdx.y * 128, bn = blockIdx.x * 64;
  const int wm = wid * 32;
  // B staging (async): 512 chunks, 2/thread
  const unsigned short* gb[2]; int obx[2];
#pragma unroll
  for (int i = 0; i < 2; ++i) {
    int lam = i * 256 + tid;
    int r = lam >> 3, cc = (lam & 7) ^ (r & 7);
    gb[i] = Bt + (size_t)(bn + r) * 512 + cc * 8;
    obx[i] = lam * 8;
  }
  // A staging (combine O0+O1, scale by 1/l, pack bf16): 1024 chunks, 4/thread
  int ar[4], ac[4], ao[4];
#pragma unroll
  for (int i = 0; i < 4; ++i) {
    int c = i * 256 + tid;
    ar[i] = c >> 3;
    ac[i] = ((c & 7) ^ (ar[i] & 7)) * 8;
    ao[i] = c * 8;
  }
  uint4 apk[4];
#pragma unroll
  for (int i = 0; i < 4; ++i) {
    size_t tok = bm + ar[i];
    float inv = 1.f / (Lb[tok * 8 + 0] + Lb[(8192 + tok) * 8 + 0]);
    const float* p0 = O0 + tok * 512 + ac[i];
    const float* p1 = O1 + tok * 512 + ac[i];
    float4 a0 = *(const float4*)p0, a1 = *(const float4*)(p0 + 4);
    float4 b0 = *(const float4*)p1, b1 = *(const float4*)(p1 + 4);
    float4 c0, c1;
    c0.x = (a0.x + b0.x) * inv; c0.y = (a0.y + b0.y) * inv;
    c0.z = (a0.z + b0.z) * inv; c0.w = (a0.w + b0.w) * inv;
    c1.x = (a1.x + b1.x) * inv; c1.y = (a1.y + b1.y) * inv;
    c1.z = (a1.z + b1.z) * inv; c1.w = (a1.w + b1.w) * inv;
    apk[i] = pk8bf(c0, c1);
  }
#pragma unroll
  for (int i = 0; i < 4; ++i) *(uint4*)(&Abuf[0][ao[i]]) = apk[i];
#pragma unroll
  for (int i = 0; i < 2; ++i) { gl2lds16(gb[i], &Bbuf[0][obx[i]]); gb[i] += 64; }

  f32x4 acc[2][4] = {};
  const int sw = li & 7;
  for (int s = 0; s < 8; ++s) {
    __syncthreads();
    const bool pf = (s + 1 < 8);
    const int p = (s + 1) & 1;
    if (pf) {
#pragma unroll
      for (int i = 0; i < 2; ++i) { gl2lds16(gb[i], &Bbuf[p][obx[i]]); gb[i] += 64; }
#pragma unroll
      for (int i = 0; i < 4; ++i) {
        size_t tok = bm + ar[i];
        float inv = 1.f / (Lb[tok * 8 + (s + 1)] + Lb[(8192 + tok) * 8 + (s + 1)]);
        const float* p0 = O0 + tok * 512 + (s + 1) * 64 + ac[i];
        const float* p1 = O1 + tok * 512 + (s + 1) * 64 + ac[i];
        float4 a0 = *(const float4*)p0, a1 = *(const float4*)(p0 + 4);
        float4 b0 = *(const float4*)p1, b1 = *(const float4*)(p1 + 4);
        float4 c0, c1;
        c0.x = (a0.x + b0.x) * inv; c0.y = (a0.y + b0.y) * inv;
        c0.z = (a0.z + b0.z) * inv; c0.w = (a0.w + b0.w) * inv;
        c1.x = (a1.x + b1.x) * inv; c1.y = (a1.y + b1.y) * inv;
        c1.z = (a1.z + b1.z) * inv; c1.w = (a1.w + b1.w) * inv;
        apk[i] = pk8bf(c0, c1);
      }
    }
    const unsigned short* As = &Abuf[s & 1][0];
    const unsigned short* Bs = &Bbuf[s & 1][0];
#pragma unroll
    for (int kk = 0; kk < 2; ++kk) {
      bf16x8 af[2], bfr[4];
#pragma unroll
      for (int t = 0; t < 2; ++t)
        af[t] = *(const bf16x8*)(As + (wm + t * 16 + li) * 64 + (((kk * 4 + quad) ^ sw) * 8));
#pragma unroll
      for (int t = 0; t < 4; ++t)
        bfr[t] = *(const bf16x8*)(Bs + (t * 16 + li) * 64 + (((kk * 4 + quad) ^ sw) * 8));
#pragma unroll
      for (int mt = 0; mt < 2; ++mt)
#pragma unroll
        for (int nt = 0; nt < 4; ++nt)
          acc[mt][nt] = __builtin_amdgcn_mfma_f32_16x16x32_bf16(af[mt], bfr[nt], acc[mt][nt], 0, 0, 0);
    }
    if (pf) {
#pragma unroll
      for (int i = 0; i < 4; ++i) *(uint4*)(&Abuf[p][ao[i]]) = apk[i];
    }
  }
#pragma unroll
  for (int mt = 0; mt < 2; ++mt)
#pragma unroll
    for (int nt = 0; nt < 4; ++nt) {
      int r0 = bm + wm + mt * 16 + quad * 4;
      int c  = bn + nt * 16 + li;
#pragma unroll
      for (int r = 0; r < 4; ++r)
        Cf[(size_t)(r0 + r) * 512 + c] = acc[mt][nt][r];
    }
}

extern "C" void kernel_launch(void* const* d_in, const int* in_sizes, int n_in,
                              void* d_out, int out_size, void* d_ws, size_t ws_size,
                              hipStream_t stream) {
  const float* q  = (const float*)d_in[0];
  const float* k  = (const float*)d_in[1];
  const float* v  = (const float*)d_in[2];
  const int* mask = (const int*)d_in[3];
  const float* Wq = (const float*)d_in[4];
  const float* Wk = (const float*)d_in[5];
  const float* Wv = (const float*)d_in[6];
  const float* Wo = (const float*)d_in[7];
  float* out = (float*)d_out;

  char* ws = (char*)d_ws;
  const size_t MB = 1024 * 1024;
  // Arena (disjoint, ~67 MB):
  unsigned short* qkvh = (unsigned short*)(ws);             // [0,24M)
  unsigned short* vtb  = (unsigned short*)(ws + 24 * MB);   // [24,32M)
  float* O0f = (float*)(ws + 32 * MB);                      // [32,48M)
  float* O1f = (float*)(ws + 48 * MB);                      // [48,64M)
  float* Lb  = (float*)(ws + 64 * MB);                      // [64,64.5M)
  unsigned short* wAll = (unsigned short*)(ws + 65 * MB);   // [65,67M)
  unsigned short* woT  = wAll + (size_t)3 * 512 * 512;

  dim3 wg(8, 8, 4);
  wtrans4<<<wg, 256, 0, stream>>>(Wq, Wk, Wv, Wo, wAll);
  const float qscale = 0.125f * 1.44269504f;  // 1/sqrt(64) * log2(e)
  dim3 gq(12, 64);
  gemm_qkv<<<gq, 256, 0, stream>>>(q, k, v, wAll, qkvh, qscale);
  dim3 vg(64, 16);
  vtrans<<<vg, 256, 0, stream>>>(qkvh, vtb);
  dim3 ag(32, 8, 4);
  attn<<<ag, 256, 0, stream>>>(qkvh, vtb, mask, O0f, O1f, Lb);
  dim3 go(8, 64);
  gemm_o<<<go, 256, 0, stream>>>(O0f, O1f, Lb, woT, out);
}

// Round 7
// 232.364 us; speedup vs baseline: 1.2381x; 1.2381x over previous
//
#include <hip/hip_runtime.h>

typedef short bf16x8 __attribute__((ext_vector_type(8)));
typedef float f32x4 __attribute__((ext_vector_type(4)));
typedef unsigned short u16x8 __attribute__((ext_vector_type(8)));

static __device__ __forceinline__ unsigned short f2bf(float f) {
  unsigned int x = __builtin_bit_cast(unsigned int, f);
  x += 0x7FFFu + ((x >> 16) & 1u);   // RNE
  return (unsigned short)(x >> 16);
}
// pack two floats' bf16 (round-half-up) into one u32 (lo=a, hi=b)
static __device__ __forceinline__ unsigned int pk2bf(float a, float b) {
  unsigned int ia = __builtin_bit_cast(unsigned int, a) + 0x8000u;
  unsigned int ib = __builtin_bit_cast(unsigned int, b) + 0x8000u;
  return __builtin_amdgcn_perm(ib, ia, 0x07060302u);
}
// async 16B global -> LDS
static __device__ __forceinline__ void gl2lds16(const unsigned short* g, unsigned short* l) {
  __builtin_amdgcn_global_load_lds(
      (const __attribute__((address_space(1))) unsigned int*)g,
      (__attribute__((address_space(3))) unsigned int*)l, 16, 0, 0);
}

// ---- q/k/v fp32 -> packed xbf[8192][1536] bf16 (8 elems/thread) ----
__global__ __launch_bounds__(256) void cvt3(const float* __restrict__ q, const float* __restrict__ k,
                                            const float* __restrict__ v,
                                            unsigned short* __restrict__ xbf) {
  const int sec = blockIdx.y;
  const float* src = (sec == 0) ? q : (sec == 1) ? k : v;
  int i = (blockIdx.x * 256 + threadIdx.x) * 8;     // over 8192*512
  int row = i >> 9, col = i & 511;
  float4 a = *(const float4*)(src + i);
  float4 b = *(const float4*)(src + i + 4);
  uint4 pk;
  pk.x = pk2bf(a.x, a.y); pk.y = pk2bf(a.z, a.w);
  pk.z = pk2bf(b.x, b.y); pk.w = pk2bf(b.z, b.w);
  *(uint4*)(xbf + (size_t)row * 1536 + sec * 512 + col) = pk;
}

// ------- 4x W [512k][512n] f32 -> WT [4][512n][512k] bf16 (z selects matrix) -------
__global__ __launch_bounds__(256) void wtrans4(const float* __restrict__ Wq, const float* __restrict__ Wk,
                                               const float* __restrict__ Wv, const float* __restrict__ Wo,
                                               unsigned short* __restrict__ WT) {
  __shared__ __align__(16) float T[64 * 68];
  const int z = blockIdx.z;
  const float* W = (z == 0) ? Wq : (z == 1) ? Wk : (z == 2) ? Wv : Wo;
  unsigned short* out = WT + (size_t)z * 512 * 512;
  const int k0 = blockIdx.x * 64, n0 = blockIdx.y * 64;
  const int tid = threadIdx.x;
#pragma unroll
  for (int i = 0; i < 4; ++i) {
    int chunk = i * 256 + tid;
    int row = chunk >> 4, fc = chunk & 15;
    *(float4*)(T + row * 68 + fc * 4) =
        *(const float4*)(W + (size_t)(k0 + row) * 512 + n0 + fc * 4);
  }
  __syncthreads();
#pragma unroll
  for (int i = 0; i < 2; ++i) {
    int chunk = i * 256 + tid;
    int nr = chunk >> 3, kc = chunk & 7;
    u16x8 v;
#pragma unroll
    for (int j = 0; j < 8; ++j) v[j] = f2bf(T[(kc * 8 + j) * 68 + nr]);
    *(u16x8*)(out + (size_t)(n0 + nr) * 512 + k0 + kc * 8) = v;
  }
}

// ---- fused QKV GEMM: C[8192][1536]. 128x128 tile, BK=32, 4x4 acc/wave, async dbuf. ----
__global__ __launch_bounds__(256) void gemm_qkv(const unsigned short* __restrict__ xbf,
                                                const unsigned short* __restrict__ Bt,
                                                unsigned short* __restrict__ C,
                                                float qscale) {
  __shared__ __align__(16) unsigned short Abuf[2][128 * 32];
  __shared__ __align__(16) unsigned short Bbuf[2][128 * 32];
  const int by = blockIdx.y;
  const unsigned short* A = xbf + (by >> 2) * 512;      // q/k/v section of packed input
  const float scale = (by < 4) ? qscale : 1.0f;
  const int tid = threadIdx.x;
  const int wid = tid >> 6, lane = tid & 63, quad = lane >> 4, li = lane & 15;
  const int bm = blockIdx.x * 128, bn = by * 128;
  const int wm = (wid & 1) * 64, wn = (wid >> 1) * 64;
  const unsigned short* ga[2]; int oa[2];
  const unsigned short* gb[2]; int obx[2];
#pragma unroll
  for (int i = 0; i < 2; ++i) {
    int lam = i * 256 + tid;                 // [0,512) chunk id
    int r = lam >> 2, c = (lam & 3) ^ (r & 3);
    ga[i] = A + (size_t)(bm + r) * 1536 + c * 8;
    oa[i] = lam * 8;
    gb[i] = Bt + (size_t)(bn + r) * 512 + c * 8;
    obx[i] = lam * 8;
  }
#pragma unroll
  for (int i = 0; i < 2; ++i) {
    gl2lds16(ga[i], &Abuf[0][oa[i]]); ga[i] += 32;
    gl2lds16(gb[i], &Bbuf[0][obx[i]]); gb[i] += 32;
  }
  f32x4 acc[4][4] = {};
  const int sw = li & 3;
  for (int s = 0; s < 16; ++s) {
    __syncthreads();
    if (s + 1 < 16) {
      int p = (s + 1) & 1;
#pragma unroll
      for (int i = 0; i < 2; ++i) {
        gl2lds16(ga[i], &Abuf[p][oa[i]]); ga[i] += 32;
        gl2lds16(gb[i], &Bbuf[p][obx[i]]); gb[i] += 32;
      }
    }
    const unsigned short* As = &Abuf[s & 1][0];
    const unsigned short* Bs = &Bbuf[s & 1][0];
    bf16x8 af[4], bfr[4];
#pragma unroll
    for (int t = 0; t < 4; ++t) {
      af[t]  = *(const bf16x8*)(As + (wm + t * 16 + li) * 32 + ((quad ^ sw) * 8));
      bfr[t] = *(const bf16x8*)(Bs + (wn + t * 16 + li) * 32 + ((quad ^ sw) * 8));
    }
#pragma unroll
    for (int mt = 0; mt < 4; ++mt)
#pragma unroll
      for (int nt = 0; nt < 4; ++nt)
        acc[mt][nt] = __builtin_amdgcn_mfma_f32_16x16x32_bf16(af[mt], bfr[nt], acc[mt][nt], 0, 0, 0);
  }
#pragma unroll
  for (int mt = 0; mt < 4; ++mt)
#pragma unroll
    for (int nt = 0; nt < 4; ++nt) {
      int r0 = bm + wm + mt * 16 + quad * 4;
      int c  = bn + wn + nt * 16 + li;
#pragma unroll
      for (int r = 0; r < 4; ++r)
        C[(size_t)(r0 + r) * 1536 + c] = f2bf(acc[mt][nt][r] * scale);
    }
}

// ---- O-proj GEMM: out[8192][512] f32 = ob[8192][512] * woT^T. 128x64, BK=64, dbuf. ----
__global__ __launch_bounds__(256) void gemm_o(const unsigned short* __restrict__ A,
                                              const unsigned short* __restrict__ Bt,
                                              float* __restrict__ Cf) {
  __shared__ __align__(16) unsigned short Abuf[2][128 * 64];
  __shared__ __align__(16) unsigned short Bbuf[2][64 * 64];
  const int K = 512, LDC = 512;
  const int tid = threadIdx.x;
  const int wid = tid >> 6, lane = tid & 63, quad = lane >> 4, li = lane & 15;
  const int bm = blockIdx.x * 128, bn = blockIdx.y * 64;
  const int wm = wid * 32;
  const unsigned short* ga[4]; int oa[4];
  const unsigned short* gb[2]; int ob[2];
#pragma unroll
  for (int i = 0; i < 4; ++i) {
    int lam = i * 256 + wid * 64 + lane;
    int r = lam >> 3, c = (lam & 7) ^ (r & 7);
    ga[i] = A + (size_t)(bm + r) * K + c * 8;
    oa[i] = lam * 8;
  }
#pragma unroll
  for (int i = 0; i < 2; ++i) {
    int lam = i * 256 + wid * 64 + lane;
    int r = lam >> 3, c = (lam & 7) ^ (r & 7);
    gb[i] = Bt + (size_t)(bn + r) * K + c * 8;
    ob[i] = lam * 8;
  }
#pragma unroll
  for (int i = 0; i < 4; ++i) { gl2lds16(ga[i], &Abuf[0][oa[i]]); ga[i] += 64; }
#pragma unroll
  for (int i = 0; i < 2; ++i) { gl2lds16(gb[i], &Bbuf[0][ob[i]]); gb[i] += 64; }

  f32x4 acc[2][4] = {};
  const int sw = li & 7;
  for (int s = 0; s < 8; ++s) {
    __syncthreads();
    if (s + 1 < 8) {
      int p = (s + 1) & 1;
#pragma unroll
      for (int i = 0; i < 4; ++i) { gl2lds16(ga[i], &Abuf[p][oa[i]]); ga[i] += 64; }
#pragma unroll
      for (int i = 0; i < 2; ++i) { gl2lds16(gb[i], &Bbuf[p][ob[i]]); gb[i] += 64; }
    }
    const unsigned short* As = &Abuf[s & 1][0];
    const unsigned short* Bs = &Bbuf[s & 1][0];
#pragma unroll
    for (int kk = 0; kk < 2; ++kk) {
      bf16x8 af[2], bfr[4];
#pragma unroll
      for (int t = 0; t < 2; ++t)
        af[t] = *(const bf16x8*)(As + (wm + t * 16 + li) * 64 + (((kk * 4 + quad) ^ sw) * 8));
#pragma unroll
      for (int t = 0; t < 4; ++t)
        bfr[t] = *(const bf16x8*)(Bs + (t * 16 + li) * 64 + (((kk * 4 + quad) ^ sw) * 8));
#pragma unroll
      for (int mt = 0; mt < 2; ++mt)
#pragma unroll
        for (int nt = 0; nt < 4; ++nt)
          acc[mt][nt] = __builtin_amdgcn_mfma_f32_16x16x32_bf16(af[mt], bfr[nt], acc[mt][nt], 0, 0, 0);
    }
  }
#pragma unroll
  for (int mt = 0; mt < 2; ++mt)
#pragma unroll
    for (int nt = 0; nt < 4; ++nt) {
      int r0 = bm + wm + mt * 16 + quad * 4;
      int c  = bn + nt * 16 + li;
#pragma unroll
      for (int r = 0; r < 4; ++r)
        Cf[(size_t)(r0 + r) * LDC + c] = acc[mt][nt][r];
    }
}

// ---- qkvh V-section -> vt [(b*8+h)*64+d][4096] (per-head V^T) ----
__global__ __launch_bounds__(256) void vtrans(const unsigned short* __restrict__ qkv,
                                              unsigned short* __restrict__ vt) {
  __shared__ __align__(16) unsigned short T[64 * 72];
  const int kt = blockIdx.x;
  const int bh = blockIdx.y;
  const int b = bh >> 3, h = bh & 7;
  const int tid = threadIdx.x;
#pragma unroll
  for (int i = 0; i < 2; ++i) {
    int chunk = i * 256 + tid;
    int row = chunk >> 3, c8 = chunk & 7;
    *(uint4*)(T + row * 72 + c8 * 8) =
        *(const uint4*)(qkv + (size_t)(b * 4096 + kt * 64 + row) * 1536 + 1024 + h * 64 + c8 * 8);
  }
  __syncthreads();
#pragma unroll
  for (int i = 0; i < 2; ++i) {
    int chunk = i * 256 + tid;
    int dr = chunk >> 3, c8 = chunk & 7;
    u16x8 v;
#pragma unroll
    for (int j = 0; j < 8; ++j) v[j] = T[(c8 * 8 + j) * 72 + dr];
    *(u16x8*)(vt + (size_t)(bh * 64 + dr) * 4096 + kt * 64 + c8 * 8) = v;
  }
}

// ---- split-K flash attention: 8 waves x 32 queries (2 q-sets/wave) = 256 q/block.
// S^T form, no-max softmax, l-via-ones-MFMA. block = (qt:256q, h, b*2+half).
// grid 512 = 2 blocks/CU (70KB LDS -> exactly 2 resident), 4 waves/SIMD;
// K/V frag reads shared by both q-sets. Writes fp32 partials + l. ----
__global__ __launch_bounds__(512) void attn(const unsigned short* __restrict__ qkv,
                                            const unsigned short* __restrict__ vt,
                                            const int* __restrict__ mask,
                                            float* __restrict__ O0, float* __restrict__ O1,
                                            float* __restrict__ Lb) {
  __shared__ __align__(16) unsigned short Kbuf[2][64 * 64];
  __shared__ __align__(16) unsigned short Vbuf[2][64 * 64];
  __shared__ __align__(16) unsigned short Psh[8][32 * 72];
  __shared__ __align__(16) unsigned short MskBits[256];
  const int qt = blockIdx.x, h = blockIdx.y, z = blockIdx.z;
  const int b = z >> 1, half = z & 1;
  const int t0 = half * 32;
  const int tid = threadIdx.x;
  const int wid = tid >> 6, lane = tid & 63, quad = lane >> 4, li = lane & 15;
  const size_t tok0 = (size_t)b * 4096;

  if (tid < 256) {
    const int4* mp = (const int4*)(mask + b * 4096 + tid * 16);
    unsigned int bits = 0;
#pragma unroll
    for (int j = 0; j < 4; ++j) {
      int4 m4 = mp[j];
      bits |= (m4.x ? 1u : 0u) << (j * 4 + 0);
      bits |= (m4.y ? 1u : 0u) << (j * 4 + 1);
      bits |= (m4.z ? 1u : 0u) << (j * 4 + 2);
      bits |= (m4.w ? 1u : 0u) << (j * 4 + 3);
    }
    MskBits[tid] = (unsigned short)bits;
  }

  // two Q B-operand sets per wave: rows qt*256 + wid*32 + {li, li+16}
  const unsigned short* qpa = qkv + (tok0 + qt * 256 + wid * 32 + li) * 1536 + h * 64;
  const unsigned short* qpb = qpa + 16 * 1536;
  bf16x8 bq0a = *(const bf16x8*)(qpa + quad * 8);
  bf16x8 bq1a = *(const bf16x8*)(qpa + 32 + quad * 8);
  bf16x8 bq0b = *(const bf16x8*)(qpb + quad * 8);
  bf16x8 bq1b = *(const bf16x8*)(qpb + 32 + quad * 8);

  // staging: waves 0-3 stage K (512 chunks), waves 4-7 stage V; 2 chunks/lane
  const unsigned short* kbase = qkv + tok0 * 1536 + 512 + h * 64;
  const unsigned short* vbase = vt + (size_t)(b * 8 + h) * 64 * 4096;
  const int wk = wid & 3;
  const int lam0 = wk * 128 + lane, lam1 = lam0 + 64;
  const int r0 = lam0 >> 3, c0 = (lam0 & 7) ^ (r0 & 7);
  const int r1 = lam1 >> 3, c1 = (lam1 & 7) ^ (r1 & 7);
  const unsigned short *g0, *g1;
  size_t kstride;
  unsigned short *lb0, *lb1;
  if (wid < 4) {
    g0 = kbase + (size_t)(t0 * 64 + r0) * 1536 + c0 * 8;
    g1 = kbase + (size_t)(t0 * 64 + r1) * 1536 + c1 * 8;
    kstride = (size_t)64 * 1536;
    lb0 = &Kbuf[0][0]; lb1 = &Kbuf[1][0];
  } else {
    g0 = vbase + (size_t)r0 * 4096 + t0 * 64 + c0 * 8;
    g1 = vbase + (size_t)r1 * 4096 + t0 * 64 + c1 * 8;
    kstride = 64;
    lb0 = &Vbuf[0][0]; lb1 = &Vbuf[1][0];
  }
  const int o0 = lam0 * 8, o1 = lam1 * 8;

  gl2lds16(g0, lb0 + o0);
  gl2lds16(g1, lb0 + o1);
  g0 += kstride; g1 += kstride;

  f32x4 accOa[4] = {}, accOb[4] = {};
  f32x4 accLa = {}, accLb = {};
  bf16x8 bones;
#pragma unroll
  for (int j = 0; j < 8; ++j) bones[j] = (short)0x3F80;  // bf16 1.0
  unsigned short* Pw = &Psh[wid][0];
  const int sw = li & 7;

  for (int tt = 0; tt < 32; ++tt) {
    const int t = t0 + tt;
    __syncthreads();
    if (tt < 31) {
      unsigned short* lb = ((tt + 1) & 1) ? lb1 : lb0;
      gl2lds16(g0, lb + o0);
      gl2lds16(g1, lb + o1);
      g0 += kstride; g1 += kstride;
    }
    const unsigned short* Ks = &Kbuf[tt & 1][0];
    const unsigned short* Vs = &Vbuf[tt & 1][0];

    // S^T = K Q^T for both q-sets; K frags shared
    f32x4 sa[4], sb[4];
#pragma unroll
    for (int kb = 0; kb < 4; ++kb) {
      const unsigned short* kr = Ks + (kb * 16 + li) * 64;
      bf16x8 ak0 = *(const bf16x8*)(kr + ((quad ^ sw) * 8));
      bf16x8 ak1 = *(const bf16x8*)(kr + (((4 + quad) ^ sw) * 8));
      f32x4 za = {}, zb = {};
      za = __builtin_amdgcn_mfma_f32_16x16x32_bf16(ak0, bq0a, za, 0, 0, 0);
      za = __builtin_amdgcn_mfma_f32_16x16x32_bf16(ak1, bq1a, za, 0, 0, 0);
      zb = __builtin_amdgcn_mfma_f32_16x16x32_bf16(ak0, bq0b, zb, 0, 0, 0);
      zb = __builtin_amdgcn_mfma_f32_16x16x32_bf16(ak1, bq1b, zb, 0, 0, 0);
      sa[kb] = za; sb[kb] = zb;
    }
    unsigned long long mbits = *(const unsigned long long*)(MskBits + t * 4);
    if (mbits != ~0ull) {
#pragma unroll
      for (int kb = 0; kb < 4; ++kb)
#pragma unroll
        for (int r = 0; r < 4; ++r) {
          int key = kb * 16 + quad * 4 + r;
          if (!((mbits >> key) & 1ull)) { sa[kb][r] = -1e30f; sb[kb][r] = -1e30f; }
        }
    }
    // p = exp2(s); pack bf16 into per-wave P (set a rows li, set b rows li+16)
#pragma unroll
    for (int kb = 0; kb < 4; ++kb) {
#pragma unroll
      for (int r = 0; r < 4; ++r) {
        sa[kb][r] = __builtin_amdgcn_exp2f(sa[kb][r]);
        sb[kb][r] = __builtin_amdgcn_exp2f(sb[kb][r]);
      }
      uint2 pka, pkb;
      pka.x = pk2bf(sa[kb][0], sa[kb][1]); pka.y = pk2bf(sa[kb][2], sa[kb][3]);
      pkb.x = pk2bf(sb[kb][0], sb[kb][1]); pkb.y = pk2bf(sb[kb][2], sb[kb][3]);
      *(uint2*)(Pw + li * 72 + kb * 16 + quad * 4) = pka;
      *(uint2*)(Pw + (li + 16) * 72 + kb * 16 + quad * 4) = pkb;
    }
    // O += P V ; l += P * ones   (V frags shared between q-sets)
    bf16x8 p0a = *(const bf16x8*)(Pw + li * 72 + quad * 8);
    bf16x8 p1a = *(const bf16x8*)(Pw + li * 72 + 32 + quad * 8);
    bf16x8 p0b = *(const bf16x8*)(Pw + (li + 16) * 72 + quad * 8);
    bf16x8 p1b = *(const bf16x8*)(Pw + (li + 16) * 72 + 32 + quad * 8);
#pragma unroll
    for (int dc = 0; dc < 4; ++dc) {
      const unsigned short* vr = Vs + (dc * 16 + li) * 64;
      bf16x8 bv0 = *(const bf16x8*)(vr + ((quad ^ sw) * 8));
      bf16x8 bv1 = *(const bf16x8*)(vr + (((4 + quad) ^ sw) * 8));
      accOa[dc] = __builtin_amdgcn_mfma_f32_16x16x32_bf16(p0a, bv0, accOa[dc], 0, 0, 0);
      accOa[dc] = __builtin_amdgcn_mfma_f32_16x16x32_bf16(p1a, bv1, accOa[dc], 0, 0, 0);
      accOb[dc] = __builtin_amdgcn_mfma_f32_16x16x32_bf16(p0b, bv0, accOb[dc], 0, 0, 0);
      accOb[dc] = __builtin_amdgcn_mfma_f32_16x16x32_bf16(p1b, bv1, accOb[dc], 0, 0, 0);
    }
    accLa = __builtin_amdgcn_mfma_f32_16x16x32_bf16(p0a, bones, accLa, 0, 0, 0);
    accLa = __builtin_amdgcn_mfma_f32_16x16x32_bf16(p1a, bones, accLa, 0, 0, 0);
    accLb = __builtin_amdgcn_mfma_f32_16x16x32_bf16(p0b, bones, accLb, 0, 0, 0);
    accLb = __builtin_amdgcn_mfma_f32_16x16x32_bf16(p1b, bones, accLb, 0, 0, 0);
  }
  // epilogue: unnormalized fp32 partials + l (accL rows align with accO rows)
  float* Oh = half ? O1 : O0;
  const size_t rqa = tok0 + qt * 256 + wid * 32 + quad * 4;
  const size_t rqb = rqa + 16;
#pragma unroll
  for (int dc = 0; dc < 4; ++dc) {
    size_t col = h * 64 + dc * 16 + li;
#pragma unroll
    for (int r = 0; r < 4; ++r) {
      Oh[(rqa + r) * 512 + col] = accOa[dc][r];
      Oh[(rqb + r) * 512 + col] = accOb[dc][r];
    }
  }
  if (li == 0) {
#pragma unroll
    for (int r = 0; r < 4; ++r) {
      Lb[((size_t)half * 8192 + rqa + r) * 8 + h] = accLa[r];
      Lb[((size_t)half * 8192 + rqb + r) * 8 + h] = accLb[r];
    }
  }
}

// ---- combine: ob = (O0+O1)/(l0+l1), bf16 ----
__global__ __launch_bounds__(256) void cmb(const float* __restrict__ O0, const float* __restrict__ O1,
                                           const float* __restrict__ Lb,
                                           unsigned short* __restrict__ ob) {
  int idx = (blockIdx.x * 256 + threadIdx.x) * 4;   // over 8192*512
  int tok = idx >> 9, h = (idx >> 6) & 7;
  float inv = 1.f / (Lb[(size_t)tok * 8 + h] + Lb[(size_t)(8192 + tok) * 8 + h]);
  float4 a = *(const float4*)(O0 + idx);
  float4 b = *(const float4*)(O1 + idx);
  uint2 pk;
  pk.x = pk2bf((a.x + b.x) * inv, (a.y + b.y) * inv);
  pk.y = pk2bf((a.z + b.z) * inv, (a.w + b.w) * inv);
  *(uint2*)(ob + idx) = pk;
}

extern "C" void kernel_launch(void* const* d_in, const int* in_sizes, int n_in,
                              void* d_out, int out_size, void* d_ws, size_t ws_size,
                              hipStream_t stream) {
  const float* q  = (const float*)d_in[0];
  const float* k  = (const float*)d_in[1];
  const float* v  = (const float*)d_in[2];
  const int* mask = (const int*)d_in[3];
  const float* Wq = (const float*)d_in[4];
  const float* Wk = (const float*)d_in[5];
  const float* Wv = (const float*)d_in[6];
  const float* Wo = (const float*)d_in[7];
  float* out = (float*)d_out;

  char* ws = (char*)d_ws;
  const size_t MB = 1024 * 1024;
  // Arena (~67 MB), time-sliced aliasing:
  //  [0,24M)   xbf (packed bf16 QKV in)  ->  O0 fp32 [0,16M) + vt/ob at [16,24M)
  //  [16,24M)  vt (after gemm_qkv)       ->  ob (after attn, written by cmb)
  //  [24,48M)  qkvh (proj output)
  //  [48,50M)  wAll (4 transposed weights)
  //  [50,66M)  O1 fp32
  //  [66M,..)  Lb (2*8192*8 fp32)
  unsigned short* xbf  = (unsigned short*)(ws);
  unsigned short* vtb  = (unsigned short*)(ws + 16 * MB);
  unsigned short* obb  = (unsigned short*)(ws + 16 * MB);
  unsigned short* qkvh = (unsigned short*)(ws + 24 * MB);
  unsigned short* wAll = (unsigned short*)(ws + 48 * MB);
  unsigned short* woT  = wAll + (size_t)3 * 512 * 512;
  float* O0f = (float*)(ws);
  float* O1f = (float*)(ws + 50 * MB);
  float* Lb  = (float*)(ws + 66 * MB);

  dim3 cg(2048, 3);
  cvt3<<<cg, 256, 0, stream>>>(q, k, v, xbf);
  dim3 wg(8, 8, 4);
  wtrans4<<<wg, 256, 0, stream>>>(Wq, Wk, Wv, Wo, wAll);
  const float qscale = 0.125f * 1.44269504f;  // 1/sqrt(64) * log2(e)
  dim3 gq(64, 12);
  gemm_qkv<<<gq, 256, 0, stream>>>(xbf, wAll, qkvh, qscale);
  dim3 vg(64, 16);
  vtrans<<<vg, 256, 0, stream>>>(qkvh, vtb);
  dim3 ag(16, 8, 4);
  attn<<<ag, 512, 0, stream>>>(qkvh, vtb, mask, O0f, O1f, Lb);
  cmb<<<4096, 256, 0, stream>>>(O0f, O1f, Lb, obb);
  dim3 go(64, 8);
  gemm_o<<<go, 256, 0, stream>>>(obb, woT, out);
}